// Round 7
// baseline (267.323 us; speedup 1.0000x reference)
//
#include <hip/hip_runtime.h>
#include <math.h>

#define NSITES 65536
#define WIN 8192
#define NW 8           // windows per sweep (schedule repeats across sweeps)
#define KN 8           // nodes per sched thread (WIN / 1024)
#define RMAX 64        // tracked rounds per window (observed depth ~9)

// ws layout:
//   recpk  uint2[2*NSITES]   1048576 B  ({site, uniform-bits} per sorted slot, per sweep)
//   ends   int  [NW*RMAX]       2048 B  (cumulative round boundaries, per window)

// wave-aggregated atomic rank: position for value v in counter array c
// (1-based values, v <= vmax; vmax wave-uniform).
__device__ __forceinline__ int agg_pos(int v, int* c, int vmax) {
  int pos = 0;
  const int lane = threadIdx.x & 63;
  for (int vv = 1; vv <= vmax; ++vv) {
    unsigned long long m = __ballot(v == vv);
    if (m) {
      int leader = __ffsll((long long)m) - 1;
      int base = 0;
      if (lane == leader) base = atomicAdd(&c[vv], (int)__popcll(m));
      base = __shfl(base, leader);
      if (v == vv) pos = base + (int)__popcll(m & ((1ull << lane) - 1ull));
    }
  }
  return pos;
}

// ---------------------------------------------------------------------------
// Kernel A: per-window DAG leveling + counting sort + packed record gather.
// One 1024-thread block per 8192-update window. Preds packed 2x16b per uint.
// ---------------------------------------------------------------------------
__global__ __launch_bounds__(1024) void GibbsSched_kernel(
    const int* __restrict__ perm, const float* __restrict__ uni,
    uint2* __restrict__ recpk, int* __restrict__ ends) {
  __shared__ unsigned short posg[NSITES];  // 128 KiB: local pos+1, 0 = absent
  __shared__ unsigned short lvl[WIN];      // 16 KiB
  __shared__ int cnt[RMAX + 1], coff[RMAX + 1];
  __shared__ int chg, bmax;
  const int tid = threadIdx.x;
  const int w = blockIdx.x;
  const int wbase = w * WIN;

  for (int g = tid; g < NSITES / 8; g += 1024)  // 8 ushorts per uint4
    ((uint4*)posg)[g] = make_uint4(0u, 0u, 0u, 0u);
  for (int i = tid; i <= RMAX; i += 1024) { cnt[i] = 0; coff[i] = 0; }
  if (tid == 0) bmax = 0;
  __syncthreads();

  int uvk[KN];
#pragma unroll
  for (int k = 0; k < KN; ++k) {
    const int lt = tid + k * 1024;
    uvk[k] = perm[wbase + lt];
    posg[uvk[k]] = (unsigned short)(lt + 1);  // sites unique within a sweep
  }
  __syncthreads();

  unsigned int predp[KN][4];  // up to 8 preds, 2x16b per uint, 0xFFFF sentinel
  int myl[KN];
#pragma unroll
  for (int k = 0; k < KN; ++k) {
    const int lt = tid + k * 1024;
    const int uv = uvk[k], u = uv >> 8, v = uv & 255;
    const int um = u ? u - 1 : 0, up = u < 255 ? u + 1 : 255;
    const int vm = v ? v - 1 : 0, vp = v < 255 ? v + 1 : 255;
    const int nb8[8] = {(um << 8) | vm, (um << 8) | v, (um << 8) | vp,
                        (u << 8) | vm,                 (u << 8) | vp,
                        (up << 8) | vm, (up << 8) | v, (up << 8) | vp};
    unsigned short pl[8];
    int np = 0;
#pragma unroll
    for (int j = 0; j < 8; ++j) {
      const int p = posg[nb8[j]];  // clipped dup == self -> p-1==lt, excluded
      if (p && p - 1 < lt) pl[np++] = (unsigned short)(p - 1);
    }
    for (int j = np; j < 8; ++j) pl[j] = 0xFFFF;
#pragma unroll
    for (int j = 0; j < 4; ++j)
      predp[k][j] = (unsigned)pl[2 * j] | ((unsigned)pl[2 * j + 1] << 16);
    lvl[lt] = 1;
    myl[k] = 1;
  }
  __syncthreads();

  // monotone Jacobi relaxation to the unique longest-path fixpoint
  for (int pass = 0; pass < 128; ++pass) {
    if (tid == 0) chg = 0;
    __syncthreads();
    bool ch = false;
#pragma unroll
    for (int k = 0; k < KN; ++k) {
      if (predp[k][0] == 0xFFFFFFFFu) continue;  // no preds: level stays 1
      int m = 0;
#pragma unroll
      for (int j = 0; j < 4; ++j) {
        const unsigned pk = predp[k][j];
        const unsigned lo = pk & 0xFFFFu, hi = pk >> 16;
        if (lo != 0xFFFFu) m = max(m, (int)lvl[lo]);
        if (hi != 0xFFFFu) m = max(m, (int)lvl[hi]);
      }
      const int nl = m + 1;  // levels only grow
      if (nl != myl[k]) {
        myl[k] = nl;
        lvl[tid + k * 1024] = (unsigned short)nl;
        ch = true;
      }
    }
    if (ch) chg = 1;
    __syncthreads();
    if (chg == 0) break;  // full no-change pass == converged
  }

#pragma unroll
  for (int k = 0; k < KN; ++k) atomicMax(&bmax, myl[k]);
  __syncthreads();
  const int vmax = bmax;

#pragma unroll
  for (int k = 0; k < KN; ++k) (void)agg_pos(myl[k], cnt, vmax);  // histogram
  __syncthreads();
  if (tid == 0) {
    int e = 0;
    for (int r = 0; r < RMAX; ++r) {  // cnt[0]==0
      coff[r] = e;
      e += cnt[r];
      ends[w * RMAX + r] = e;  // cumulative end through round r
    }
  }
  __syncthreads();

#pragma unroll
  for (int k = 0; k < KN; ++k) {
    const int pos = agg_pos(myl[k], coff, vmax);
    const int lt = tid + k * 1024;
    const int gp = wbase + pos;
    recpk[gp] = make_uint2((unsigned)uvk[k],
                           __float_as_uint(uni[wbase + lt]));          // sweep 0
    recpk[NSITES + gp] = make_uint2((unsigned)uvk[k],
                                    __float_as_uint(uni[NSITES + wbase + lt]));
  }
}

// ---------------------------------------------------------------------------
// Kernel B: executor — 1 block x 1024 threads.
// Per update: 3 row-window LDS reads -> neighbor histogram -> 4 scalar
// cum-prob reads -> 4 compares -> byte write. Tail rounds (<=64 left) run on
// a single wave without block barriers.
// ---------------------------------------------------------------------------
__device__ __forceinline__ void do_update(unsigned char* cell,
                                          const unsigned int* cellw,
                                          const float* c0a, const float* c1a,
                                          const float* c2a, const float* c3a,
                                          unsigned uvv, float r) {
  const int u = uvv >> 8, v = (int)(uvv & 255u);
  const int um = u ? u - 1 : 0, up = u < 255 ? u + 1 : 255;
  const int vm = v ? v - 1 : 0, vp = v < 255 ? v + 1 : 255;
  const int cb = vm >> 2;              // dword col of 8-byte window start
  const int sh0 = (vm & 3) << 3;
  const int shv = (v - vm) << 3;       // 0 or 8
  const int shp = (vp - vm) << 3;      // 8 or 16 (or 8 at right border)
  int acc = 0;  // per-class counts in nibbles (class 4 -> bit16, unused)
  {  // top row: cols vm, v, vp (clipped dups included, matching reference)
    const unsigned int* rw = cellw + (um << 6) + cb;
    const unsigned long long wd =
        ((unsigned long long)rw[1] << 32) | (unsigned long long)rw[0];
    const unsigned wl = (unsigned)(wd >> sh0);
    acc += 1 << ((wl & 255u) << 2);
    acc += 1 << (((wl >> shv) & 255u) << 2);
    acc += 1 << (((wl >> shp) & 255u) << 2);
  }
  {  // middle row: cols vm, vp only (true center excluded exactly once)
    const unsigned int* rw = cellw + (u << 6) + cb;
    const unsigned long long wd =
        ((unsigned long long)rw[1] << 32) | (unsigned long long)rw[0];
    const unsigned wl = (unsigned)(wd >> sh0);
    acc += 1 << ((wl & 255u) << 2);
    acc += 1 << (((wl >> shp) & 255u) << 2);
  }
  {  // bottom row: cols vm, v, vp
    const unsigned int* rw = cellw + (up << 6) + cb;
    const unsigned long long wd =
        ((unsigned long long)rw[1] << 32) | (unsigned long long)rw[0];
    const unsigned wl = (unsigned)(wd >> sh0);
    acc += 1 << ((wl & 255u) << 2);
    acc += 1 << (((wl >> shv) & 255u) << 2);
    acc += 1 << (((wl >> shp) & 255u) << 2);
  }
  const int n0 = acc & 15, n1 = (acc >> 4) & 15, n2 = (acc >> 8) & 15;
  const int idx = n0 + 9 * n1 + 81 * n2;
  int cnt = (c0a[idx] < r) ? 1 : 0;
  cnt += (c1a[idx] < r) ? 1 : 0;
  cnt += (c2a[idx] < r) ? 1 : 0;
  cnt += (c3a[idx] < r) ? 1 : 0;
  cell[uvv] = (unsigned char)cnt;  // 0..4
}

__global__ __launch_bounds__(1024) void GibbsSampler_90443421319469_kernel(
    const int* __restrict__ Xi, const uint2* __restrict__ recpk,
    const float* __restrict__ betap, const int* __restrict__ ends,
    int* __restrict__ out) {
#pragma clang fp contract(off)
  __shared__ __align__(16) unsigned int cellw[NSITES / 4];  // 64 KiB lattice
  __shared__ float c0a[729], c1a[729], c2a[729], c3a[729];  // 11.4 KiB
  __shared__ int lend[NW * RMAX];                           // 2 KiB
  unsigned char* cell = (unsigned char*)cellw;
  const int tid = threadIdx.x;
  const float beta = betap[0];

  for (int g = tid; g < NSITES / 4; g += 1024) {
    int4 x = ((const int4*)Xi)[g];
    cellw[g] = (unsigned)(x.x & 255) | ((unsigned)(x.y & 255) << 8) |
               ((unsigned)(x.z & 255) << 16) | ((unsigned)(x.w & 255) << 24);
  }
  if (tid < NW * RMAX) lend[tid] = ends[tid];
  // cumulative softmax table: bit-identical to per-update reference math
  for (int t = tid; t < 729; t += 1024) {
    const int n0 = t % 9, n1 = (t / 9) % 9, n2 = t / 81;
    const int n3 = 8 - n0 - n1 - n2;
    float v0 = 2.f, v1 = 2.f, v2 = 2.f, v3 = 2.f;  // unreachable combos
    if (n3 >= 0) {
      const int mx = max(max(n0, n1), max(n2, n3));
      const float xm = beta * (float)mx;   // fl(beta*mx), no FMA (contract off)
      const float x0 = beta * (float)n0;
      const float x1 = beta * (float)n1;
      const float x2 = beta * (float)n2;
      const float x3 = beta * (float)n3;
      const float e0 = (float)exp((double)(x0 - xm));
      const float e1 = (float)exp((double)(x1 - xm));
      const float e2 = (float)exp((double)(x2 - xm));
      const float e3 = (float)exp((double)(x3 - xm));
      const float s = ((e0 + e1) + e2) + e3;  // sequential sum, like np/XLA
      v0 = e0 / s;                            // IEEE f32 divides, like ref
      v1 = v0 + e1 / s;
      v2 = v1 + e2 / s;
      v3 = v2 + e3 / s;
    }
    c0a[t] = v0; c1a[t] = v1; c2a[t] = v2; c3a[t] = v3;
  }
  __syncthreads();

  for (int w = 0; w < 2 * NW; ++w) {
    const int ww = w & (NW - 1);
    const int sw = w >> 3;  // sweep index (NW==8)
    const uint2* rp = recpk + sw * NSITES + ww * WIN;
    const int* le = &lend[ww * RMAX];

    int nb = 0, ne = le[1];
    uint2 cur = make_uint2(0u, 0u);
    if (tid < ne) cur = rp[tid];  // round-1 first-iteration record

    for (int rd = 1; rd < RMAX; ++rd) {
      const int b = nb, e = ne;
      if (b >= WIN) break;  // uniform: window complete

      if (WIN - b <= 64) {
        // -------- single-wave tail: no block barriers between rounds ------
        if (tid < 64) {
          const int i = b + tid;
          int myrd = 0;
          uint2 rc = make_uint2(0u, 0u);
          if (i < WIN) {
            myrd = rd;
            while (le[myrd] <= i) ++myrd;  // le monotone, reaches WIN
            rc = rp[i];
          }
          int mx = myrd;
#pragma unroll
          for (int off = 1; off < 64; off <<= 1)
            mx = max(mx, __shfl_xor(mx, off));
          for (int rr = rd; rr <= mx; ++rr) {
            // intra-wave LDS ordering: ds ops issue in order; compiler adds
            // lgkmcnt waits for the cell write->read dependences
            if (myrd == rr)
              do_update(cell, cellw, c0a, c1a, c2a, c3a, rc.x,
                        __uint_as_float(rc.y));
          }
        }
        __syncthreads();
        break;  // window complete
      }

      nb = e;
      ne = (rd + 1 < RMAX) ? le[rd + 1] : e;
      // prefetch next round's first-iter record (read-only stream)
      uint2 nxt = make_uint2(0u, 0u);
      if (nb + tid < ne) nxt = rp[nb + tid];
      // execute current round
      if (b + tid < e)
        do_update(cell, cellw, c0a, c1a, c2a, c3a, cur.x,
                  __uint_as_float(cur.y));
      for (int i = b + tid + 1024; i < e; i += 1024) {
        const uint2 rc = rp[i];
        do_update(cell, cellw, c0a, c1a, c2a, c3a, rc.x,
                  __uint_as_float(rc.y));
      }
      __syncthreads();  // round rd writes before round rd+1 reads
      cur = nxt;
    }
  }

  for (int g = tid; g < NSITES / 4; g += 1024) {
    const unsigned p = cellw[g];
    int4 o;
    o.x = (int)(p & 255u);
    o.y = (int)((p >> 8) & 255u);
    o.z = (int)((p >> 16) & 255u);
    o.w = (int)((p >> 24) & 255u);
    ((int4*)out)[g] = o;
  }
}

extern "C" void kernel_launch(void* const* d_in, const int* in_sizes, int n_in,
                              void* d_out, int out_size, void* d_ws,
                              size_t ws_size, hipStream_t stream) {
  const int* Xi = (const int*)d_in[0];
  const int* perm = (const int*)d_in[1];
  const float* uni = (const float*)d_in[2];
  const float* beta = (const float*)d_in[3];
  int* out = (int*)d_out;

  char* ws = (char*)d_ws;
  uint2* recpk = (uint2*)ws;                 // 1 MiB
  int* ends = (int*)(ws + 2 * NSITES * 8);   // 2 KiB

  GibbsSched_kernel<<<dim3(NW), dim3(1024), 0, stream>>>(perm, uni, recpk,
                                                         ends);
  GibbsSampler_90443421319469_kernel<<<dim3(1), dim3(1024), 0, stream>>>(
      Xi, recpk, beta, ends, out);
}

// Round 8
// 248.522 us; speedup vs baseline: 1.0756x; 1.0756x over previous
//
#include <hip/hip_runtime.h>
#include <math.h>

#define NSITES 65536
#define WIN 8192
#define NW 8           // windows per sweep (schedule repeats across sweeps)
#define KN 8           // nodes per sched thread (WIN / 1024)
#define RMAX 64        // tracked rounds per window (observed depth ~11)

// ws layout:
//   recpk  uint2[2*NSITES]   1048576 B  ({site, uniform-bits} per sorted slot, per sweep)
//   ends   int  [NW*RMAX]       2048 B  (cumulative round boundaries, per window)
//   preds  uint4[NSITES]      1048576 B  (8 packed 16b pred positions per node)

// wave-aggregated atomic rank: position for value v in counter array c
// (1-based values, v <= vmax; vmax wave-uniform).
__device__ __forceinline__ int agg_pos(int v, int* c, int vmax) {
  int pos = 0;
  const int lane = threadIdx.x & 63;
  for (int vv = 1; vv <= vmax; ++vv) {
    unsigned long long m = __ballot(v == vv);
    if (m) {
      int leader = __ffsll((long long)m) - 1;
      int base = 0;
      if (lane == leader) base = atomicAdd(&c[vv], (int)__popcll(m));
      base = __shfl(base, leader);
      if (v == vv) pos = base + (int)__popcll(m & ((1ull << lane) - 1ull));
    }
  }
  return pos;
}

// ---------------------------------------------------------------------------
// Kernel A1: predecessor extraction. 64 blocks = (window w, chunk c); each
// block scatters its window's position grid into LDS and emits the packed
// pred-position list (16b each, 0xFFFF sentinel) for its 1024 nodes.
// ---------------------------------------------------------------------------
__global__ __launch_bounds__(1024) void GibbsPred_kernel(
    const int* __restrict__ perm, uint4* __restrict__ preds) {
  __shared__ unsigned short posg[NSITES];  // 128 KiB: window pos+1, 0 = absent
  const int tid = threadIdx.x;
  const int w = blockIdx.x >> 3;
  const int c = blockIdx.x & 7;
  const int wbase = w * WIN;

  for (int g = tid; g < NSITES / 8; g += 1024)  // 8 ushorts per uint4
    ((uint4*)posg)[g] = make_uint4(0u, 0u, 0u, 0u);
  __syncthreads();

#pragma unroll
  for (int k = 0; k < KN; ++k) {
    const int lt = k * 1024 + tid;
    posg[perm[wbase + lt]] = (unsigned short)(lt + 1);  // sites unique/sweep
  }
  __syncthreads();

  const int lt = c * 1024 + tid;
  const int uv = perm[wbase + lt], u = uv >> 8, v = uv & 255;
  const int um = u ? u - 1 : 0, up = u < 255 ? u + 1 : 255;
  const int vm = v ? v - 1 : 0, vp = v < 255 ? v + 1 : 255;
  const int nb8[8] = {(um << 8) | vm, (um << 8) | v, (um << 8) | vp,
                      (u << 8) | vm,                 (u << 8) | vp,
                      (up << 8) | vm, (up << 8) | v, (up << 8) | vp};
  unsigned short pl[8];
  int np = 0;
#pragma unroll
  for (int j = 0; j < 8; ++j) {
    const int p = posg[nb8[j]];  // clipped dup == self -> p-1==lt, excluded
    if (p && p - 1 < lt) pl[np++] = (unsigned short)(p - 1);
  }
  for (int j = np; j < 8; ++j) pl[j] = 0xFFFF;
  preds[wbase + lt] =
      make_uint4((unsigned)pl[0] | ((unsigned)pl[1] << 16),
                 (unsigned)pl[2] | ((unsigned)pl[3] << 16),
                 (unsigned)pl[4] | ((unsigned)pl[5] << 16),
                 (unsigned)pl[6] | ((unsigned)pl[7] << 16));
}

// ---------------------------------------------------------------------------
// Kernel A2: chunk-sequential leveling + counting sort + record gather.
// One 1024-thread block per window. Chunk c's preds in chunks <c are final;
// only nodes with intra-chunk preds (~6%) run Jacobi micro-passes.
// ---------------------------------------------------------------------------
__global__ __launch_bounds__(1024) void GibbsSched_kernel(
    const int* __restrict__ perm, const float* __restrict__ uni,
    const uint4* __restrict__ preds, uint2* __restrict__ recpk,
    int* __restrict__ ends) {
  __shared__ unsigned short lvl[WIN];  // 16 KiB
  __shared__ int cnt[RMAX + 1], coff[RMAX + 1];
  __shared__ int chg, bmax;
  const int tid = threadIdx.x;
  const int w = blockIdx.x;
  const int wbase = w * WIN;

  for (int i = tid; i <= RMAX; i += 1024) { cnt[i] = 0; coff[i] = 0; }
  if (tid == 0) bmax = 0;
  __syncthreads();

  int myl[KN];
  for (int c = 0; c < KN; ++c) {
    const int lt = c * 1024 + tid;
    const uint4 pp = preds[wbase + lt];
    const unsigned ent[8] = {pp.x & 0xFFFFu, pp.x >> 16, pp.y & 0xFFFFu,
                             pp.y >> 16,     pp.z & 0xFFFFu, pp.z >> 16,
                             pp.w & 0xFFFFu, pp.w >> 16};
    int basemax = 0;          // max level over finalized (earlier-chunk) preds
    unsigned short intr[8];   // intra-chunk pred positions
    int nin = 0;
#pragma unroll
    for (int j = 0; j < 8; ++j) {
      const unsigned p = ent[j];
      if (p == 0xFFFFu) continue;
      if ((int)p < c * 1024) basemax = max(basemax, (int)lvl[p]);
      else intr[nin++] = (unsigned short)p;  // p in [c*1024, lt)
    }
    int ml = basemax + 1;  // init from below (<= final level)
    lvl[lt] = (unsigned short)ml;
    __syncthreads();

    // Jacobi micro-passes over intra-chunk chains (rare, depth ~2)
    for (;;) {
      if (tid == 0) chg = 0;
      __syncthreads();
      bool ch = false;
      if (nin) {
        int m = basemax;
        for (int j = 0; j < nin; ++j) m = max(m, (int)lvl[intr[j]]);
        const int nl = m + 1;
        if (nl != ml) { ml = nl; lvl[lt] = (unsigned short)nl; ch = true; }
      }
      if (ch) chg = 1;
      __syncthreads();
      if (chg == 0) break;  // full no-change pass == chunk converged
    }
    myl[c] = ml;
  }

#pragma unroll
  for (int k = 0; k < KN; ++k) atomicMax(&bmax, myl[k]);
  __syncthreads();
  const int vmax = bmax;

#pragma unroll
  for (int k = 0; k < KN; ++k) (void)agg_pos(myl[k], cnt, vmax);  // histogram
  __syncthreads();
  if (tid == 0) {
    int e = 0;
    for (int r = 0; r < RMAX; ++r) {  // cnt[0]==0
      coff[r] = e;
      e += cnt[r];
      ends[w * RMAX + r] = e;  // cumulative end through round r
    }
  }
  __syncthreads();

#pragma unroll
  for (int k = 0; k < KN; ++k) {
    const int pos = agg_pos(myl[k], coff, vmax);
    const int lt = tid + k * 1024;
    const int gp = wbase + pos;
    const unsigned uvv = (unsigned)perm[wbase + lt];
    recpk[gp] = make_uint2(uvv, __float_as_uint(uni[wbase + lt]));  // sweep 0
    recpk[NSITES + gp] =
        make_uint2(uvv, __float_as_uint(uni[NSITES + wbase + lt]));
  }
}

// ---------------------------------------------------------------------------
// Kernel B: executor — 1 block x 1024 threads (unchanged from R7; 124 us).
// ---------------------------------------------------------------------------
__device__ __forceinline__ void do_update(unsigned char* cell,
                                          const unsigned int* cellw,
                                          const float* c0a, const float* c1a,
                                          const float* c2a, const float* c3a,
                                          unsigned uvv, float r) {
  const int u = uvv >> 8, v = (int)(uvv & 255u);
  const int um = u ? u - 1 : 0, up = u < 255 ? u + 1 : 255;
  const int vm = v ? v - 1 : 0, vp = v < 255 ? v + 1 : 255;
  const int cb = vm >> 2;              // dword col of 8-byte window start
  const int sh0 = (vm & 3) << 3;
  const int shv = (v - vm) << 3;       // 0 or 8
  const int shp = (vp - vm) << 3;      // 8 or 16 (or 8 at right border)
  int acc = 0;  // per-class counts in nibbles (class 4 -> bit16, unused)
  {  // top row: cols vm, v, vp (clipped dups included, matching reference)
    const unsigned int* rw = cellw + (um << 6) + cb;
    const unsigned long long wd =
        ((unsigned long long)rw[1] << 32) | (unsigned long long)rw[0];
    const unsigned wl = (unsigned)(wd >> sh0);
    acc += 1 << ((wl & 255u) << 2);
    acc += 1 << (((wl >> shv) & 255u) << 2);
    acc += 1 << (((wl >> shp) & 255u) << 2);
  }
  {  // middle row: cols vm, vp only (true center excluded exactly once)
    const unsigned int* rw = cellw + (u << 6) + cb;
    const unsigned long long wd =
        ((unsigned long long)rw[1] << 32) | (unsigned long long)rw[0];
    const unsigned wl = (unsigned)(wd >> sh0);
    acc += 1 << ((wl & 255u) << 2);
    acc += 1 << (((wl >> shp) & 255u) << 2);
  }
  {  // bottom row: cols vm, v, vp
    const unsigned int* rw = cellw + (up << 6) + cb;
    const unsigned long long wd =
        ((unsigned long long)rw[1] << 32) | (unsigned long long)rw[0];
    const unsigned wl = (unsigned)(wd >> sh0);
    acc += 1 << ((wl & 255u) << 2);
    acc += 1 << (((wl >> shv) & 255u) << 2);
    acc += 1 << (((wl >> shp) & 255u) << 2);
  }
  const int n0 = acc & 15, n1 = (acc >> 4) & 15, n2 = (acc >> 8) & 15;
  const int idx = n0 + 9 * n1 + 81 * n2;
  int cnt = (c0a[idx] < r) ? 1 : 0;
  cnt += (c1a[idx] < r) ? 1 : 0;
  cnt += (c2a[idx] < r) ? 1 : 0;
  cnt += (c3a[idx] < r) ? 1 : 0;
  cell[uvv] = (unsigned char)cnt;  // 0..4
}

__global__ __launch_bounds__(1024) void GibbsSampler_90443421319469_kernel(
    const int* __restrict__ Xi, const uint2* __restrict__ recpk,
    const float* __restrict__ betap, const int* __restrict__ ends,
    int* __restrict__ out) {
#pragma clang fp contract(off)
  __shared__ __align__(16) unsigned int cellw[NSITES / 4];  // 64 KiB lattice
  __shared__ float c0a[729], c1a[729], c2a[729], c3a[729];  // 11.4 KiB
  __shared__ int lend[NW * RMAX];                           // 2 KiB
  unsigned char* cell = (unsigned char*)cellw;
  const int tid = threadIdx.x;
  const float beta = betap[0];

  for (int g = tid; g < NSITES / 4; g += 1024) {
    int4 x = ((const int4*)Xi)[g];
    cellw[g] = (unsigned)(x.x & 255) | ((unsigned)(x.y & 255) << 8) |
               ((unsigned)(x.z & 255) << 16) | ((unsigned)(x.w & 255) << 24);
  }
  if (tid < NW * RMAX) lend[tid] = ends[tid];
  // cumulative softmax table: bit-identical to per-update reference math
  for (int t = tid; t < 729; t += 1024) {
    const int n0 = t % 9, n1 = (t / 9) % 9, n2 = t / 81;
    const int n3 = 8 - n0 - n1 - n2;
    float v0 = 2.f, v1 = 2.f, v2 = 2.f, v3 = 2.f;  // unreachable combos
    if (n3 >= 0) {
      const int mx = max(max(n0, n1), max(n2, n3));
      const float xm = beta * (float)mx;   // fl(beta*mx), no FMA (contract off)
      const float x0 = beta * (float)n0;
      const float x1 = beta * (float)n1;
      const float x2 = beta * (float)n2;
      const float x3 = beta * (float)n3;
      const float e0 = (float)exp((double)(x0 - xm));
      const float e1 = (float)exp((double)(x1 - xm));
      const float e2 = (float)exp((double)(x2 - xm));
      const float e3 = (float)exp((double)(x3 - xm));
      const float s = ((e0 + e1) + e2) + e3;  // sequential sum, like np/XLA
      v0 = e0 / s;                            // IEEE f32 divides, like ref
      v1 = v0 + e1 / s;
      v2 = v1 + e2 / s;
      v3 = v2 + e3 / s;
    }
    c0a[t] = v0; c1a[t] = v1; c2a[t] = v2; c3a[t] = v3;
  }
  __syncthreads();

  for (int w = 0; w < 2 * NW; ++w) {
    const int ww = w & (NW - 1);
    const int sw = w >> 3;  // sweep index (NW==8)
    const uint2* rp = recpk + sw * NSITES + ww * WIN;
    const int* le = &lend[ww * RMAX];

    int nb = 0, ne = le[1];
    uint2 cur = make_uint2(0u, 0u);
    if (tid < ne) cur = rp[tid];  // round-1 first-iteration record

    for (int rd = 1; rd < RMAX; ++rd) {
      const int b = nb, e = ne;
      if (b >= WIN) break;  // uniform: window complete

      if (WIN - b <= 64) {
        // -------- single-wave tail: no block barriers between rounds ------
        if (tid < 64) {
          const int i = b + tid;
          int myrd = 0;
          uint2 rc = make_uint2(0u, 0u);
          if (i < WIN) {
            myrd = rd;
            while (le[myrd] <= i) ++myrd;  // le monotone, reaches WIN
            rc = rp[i];
          }
          int mx = myrd;
#pragma unroll
          for (int off = 1; off < 64; off <<= 1)
            mx = max(mx, __shfl_xor(mx, off));
          for (int rr = rd; rr <= mx; ++rr) {
            // intra-wave LDS ordering: ds ops issue in order; compiler adds
            // lgkmcnt waits for the cell write->read dependences
            if (myrd == rr)
              do_update(cell, cellw, c0a, c1a, c2a, c3a, rc.x,
                        __uint_as_float(rc.y));
          }
        }
        __syncthreads();
        break;  // window complete
      }

      nb = e;
      ne = (rd + 1 < RMAX) ? le[rd + 1] : e;
      // prefetch next round's first-iter record (read-only stream)
      uint2 nxt = make_uint2(0u, 0u);
      if (nb + tid < ne) nxt = rp[nb + tid];
      // execute current round
      if (b + tid < e)
        do_update(cell, cellw, c0a, c1a, c2a, c3a, cur.x,
                  __uint_as_float(cur.y));
      for (int i = b + tid + 1024; i < e; i += 1024) {
        const uint2 rc = rp[i];
        do_update(cell, cellw, c0a, c1a, c2a, c3a, rc.x,
                  __uint_as_float(rc.y));
      }
      __syncthreads();  // round rd writes before round rd+1 reads
      cur = nxt;
    }
  }

  for (int g = tid; g < NSITES / 4; g += 1024) {
    const unsigned p = cellw[g];
    int4 o;
    o.x = (int)(p & 255u);
    o.y = (int)((p >> 8) & 255u);
    o.z = (int)((p >> 16) & 255u);
    o.w = (int)((p >> 24) & 255u);
    ((int4*)out)[g] = o;
  }
}

extern "C" void kernel_launch(void* const* d_in, const int* in_sizes, int n_in,
                              void* d_out, int out_size, void* d_ws,
                              size_t ws_size, hipStream_t stream) {
  const int* Xi = (const int*)d_in[0];
  const int* perm = (const int*)d_in[1];
  const float* uni = (const float*)d_in[2];
  const float* beta = (const float*)d_in[3];
  int* out = (int*)d_out;

  char* ws = (char*)d_ws;
  uint2* recpk = (uint2*)ws;                     // 1 MiB
  int* ends = (int*)(ws + 2 * NSITES * 8);       // 2 KiB
  uint4* preds = (uint4*)(ws + 2 * NSITES * 8 + 4096);  // 1 MiB (aligned)

  GibbsPred_kernel<<<dim3(NW * 8), dim3(1024), 0, stream>>>(perm, preds);
  GibbsSched_kernel<<<dim3(NW), dim3(1024), 0, stream>>>(perm, uni, preds,
                                                         recpk, ends);
  GibbsSampler_90443421319469_kernel<<<dim3(1), dim3(1024), 0, stream>>>(
      Xi, recpk, beta, ends, out);
}